// Round 14
// baseline (3368.707 us; speedup 1.0000x reference)
//
#include <hip/hip_runtime.h>
#include <hip/hip_bf16.h>
#include <hip/hip_cooperative_groups.h>
#include <math.h>

namespace cg = cooperative_groups;

// Problem constants
#define BB 2
#define LL 1024
#define DD 768
#define NN 16
#define FF 3072
#define VV 32000
#define NLL 4
#define NSS 3
#define BL (BB*LL)    // 2048
#define CHK 64        // scan chunks
#define CLEN (LL/CHK) // 16

typedef __bf16 bf16x8 __attribute__((ext_vector_type(8)));
typedef float f32x4 __attribute__((ext_vector_type(4)));
typedef short short8 __attribute__((ext_vector_type(8)));
typedef short short4v __attribute__((ext_vector_type(4)));

typedef __attribute__((address_space(1))) const void gconst_t;
typedef __attribute__((address_space(3))) void lds_t;

__device__ __forceinline__ void g2l16(const void* g, void* l) {
  __builtin_amdgcn_global_load_lds((gconst_t*)g, (lds_t*)l, 16, 0, 0);
}

// T2 XOR-swizzle (rule #21): LDS linear; global SOURCE pre-swizzled;
// read XORs the same involution. stage: ((lane&7)^(lane>>3))*8
// read: ((kk*4+(lane>>4))^(lane&7))*8

// ---------------- elementwise kernels ----------------

// embed, float4-vectorized: grid 1536 x 256 (one float4 per thread).
__global__ __launch_bounds__(256) void k_embed(
    const int* __restrict__ x, const float* __restrict__ emb,
    float* __restrict__ h) {
  int gid = blockIdx.x * 256 + threadIdx.x;   // 0..393215
  int row = gid / 192;
  int g = (gid - row * 192) * 4;
  int idx = x[row];
  *(float4*)&h[(size_t)row * DD + g] =
      *(const float4*)&emb[(size_t)idx * DD + g];
}

// conv + silu -> ub (bf16), float4-vectorized. grid 1536 x 256.
__global__ __launch_bounds__(256) void k_conv(
    const float* __restrict__ h, const float* __restrict__ cw,
    __hip_bfloat16* __restrict__ ub) {
  int gid = blockIdx.x * 256 + threadIdx.x;   // 0..393215
  int row = gid / 192;
  int g = gid - row * 192;
  int d0 = g * 4;
  int l = row & (LL - 1);
  float4 h0 = *(const float4*)&h[(size_t)row * DD + d0];
  float4 h1, h2;
  if (l >= 1) h1 = *(const float4*)&h[(size_t)(row - 1) * DD + d0];
  else { h1.x = h1.y = h1.z = h1.w = 0.f; }
  if (l >= 2) h2 = *(const float4*)&h[(size_t)(row - 2) * DD + d0];
  else { h2.x = h2.y = h2.z = h2.w = 0.f; }
  const float* hp0 = (const float*)&h0;
  const float* hp1 = (const float*)&h1;
  const float* hp2 = (const float*)&h2;
  alignas(8) __hip_bfloat16 o[4];
  #pragma unroll
  for (int i = 0; i < 4; ++i) {
    int d = d0 + i;
    float v = hp2[i] * cw[d * 3 + 0] + hp1[i] * cw[d * 3 + 1] + hp0[i] * cw[d * 3 + 2];
    float sv = v / (1.f + __expf(-v));
    o[i] = __float2bfloat16(sv);
  }
  *(short4v*)&ub[(size_t)row * DD + d0] = *(short4v*)o;
}

__global__ __launch_bounds__(256) void k_layernorm(
    const float* __restrict__ x, const float* __restrict__ g,
    const float* __restrict__ bta, __hip_bfloat16* __restrict__ o) {
  int row = blockIdx.x;
  const float* xr = x + (size_t)row * DD;
  int tid = threadIdx.x;
  float v1 = xr[tid], v2 = xr[tid + 256], v3 = xr[tid + 512];
  float s = v1 + v2 + v3;
  float sq = v1 * v1 + v2 * v2 + v3 * v3;
  #pragma unroll
  for (int m = 1; m < 64; m <<= 1) {
    s  += __shfl_xor(s, m);
    sq += __shfl_xor(sq, m);
  }
  __shared__ float ss[4], sqs[4];
  if ((tid & 63) == 0) { ss[tid >> 6] = s; sqs[tid >> 6] = sq; }
  __syncthreads();
  s  = ss[0] + ss[1] + ss[2] + ss[3];
  sq = sqs[0] + sqs[1] + sqs[2] + sqs[3];
  float mean = s * (1.f / DD);
  float var  = sq * (1.f / DD) - mean * mean;
  float rstd = rsqrtf(var + 1e-5f);
  o[(size_t)row * DD + tid]       = __float2bfloat16((v1 - mean) * rstd * g[tid]       + bta[tid]);
  o[(size_t)row * DD + tid + 256] = __float2bfloat16((v2 - mean) * rstd * g[tid + 256] + bta[tid + 256]);
  o[(size_t)row * DD + tid + 512] = __float2bfloat16((v3 - mean) * rstd * g[tid + 512] + bta[tid + 512]);
}

// ---------------- batched weight convert+transpose (vectorized) -------------
#define S1 1728
#define S2 1740
#define S3 4044
#define S4 6348
#define SEND 12348

__global__ __launch_bounds__(256) void k_wconv_all(
    const float* __restrict__ Wdt, const float* __restrict__ WB,
    const float* __restrict__ WC, const float* __restrict__ W1,
    const float* __restrict__ W2, const float* __restrict__ Wout,
    __hip_bfloat16* __restrict__ WTdt, __hip_bfloat16* __restrict__ WT1,
    __hip_bfloat16* __restrict__ WT2, __hip_bfloat16* __restrict__ WTlog) {
  __shared__ float T[64][65];
  int bid = blockIdx.x;
  int tid = threadIdx.x;

  if (bid >= S1 && bid < S2) {   // B/C strips
    int sub = bid - S1;
    const float* WBp = WB + (size_t)sub * DD * NN;
    const float* WCp = WC + (size_t)sub * DD * NN;
    __hip_bfloat16* dst = WTdt + (size_t)sub * 832 * DD;
    for (int e = tid; e < 64 * DD; e += 256) {
      int r = e / DD, k = e - (e / DD) * DD;
      float v = 0.f;
      if (r < 16)      v = WBp[(size_t)k * NN + r];
      else if (r < 32) v = WCp[(size_t)k * NN + (r - 16)];
      dst[(size_t)(768 + r) * DD + k] = __float2bfloat16(v);
    }
    return;
  }

  const float* W; __hip_bfloat16* WT;
  int K, N, n0, k0;
  if (bid < S1) {
    int sub = bid / 144, t = bid % 144;
    W = Wdt + (size_t)sub * DD * DD; WT = WTdt + (size_t)sub * 832 * DD;
    K = DD; N = DD; n0 = (t % 12) * 64; k0 = (t / 12) * 64;
  } else if (bid < S3) {
    int idx = bid - S2, l = idx / 576, t = idx % 576;
    W = W1 + (size_t)l * DD * FF; WT = WT1 + (size_t)l * FF * DD;
    K = DD; N = FF; n0 = (t % 48) * 64; k0 = (t / 48) * 64;
  } else if (bid < S4) {
    int idx = bid - S3, l = idx / 576, t = idx % 576;
    W = W2 + (size_t)l * FF * DD; WT = WT2 + (size_t)l * DD * FF;
    K = FF; N = DD; n0 = (t % 12) * 64; k0 = (t / 12) * 64;
  } else {
    int t = bid - S4;
    W = Wout; WT = WTlog;
    K = DD; N = VV; n0 = (t % 500) * 64; k0 = (t / 500) * 64;
  }

  // load: float4 per lane (16 B)
  {
    int r0 = tid >> 4, c4 = (tid & 15) * 4;
    #pragma unroll
    for (int i = 0; i < 4; ++i) {
      int r = r0 + 16 * i;
      float4 v = *(const float4*)&W[(size_t)(k0 + r) * N + n0 + c4];
      T[r][c4 + 0] = v.x;
      T[r][c4 + 1] = v.y;
      T[r][c4 + 2] = v.z;
      T[r][c4 + 3] = v.w;
    }
  }
  __syncthreads();
  // store: bf16x8 per lane (16 B), 8 lanes cover one 64-col row
  {
    int c8 = tid & 7;
    #pragma unroll
    for (int j = 0; j < 2; ++j) {
      int n_l = (tid >> 3) + 32 * j;
      alignas(16) __hip_bfloat16 ox[8];
      #pragma unroll
      for (int i = 0; i < 8; ++i)
        ox[i] = __float2bfloat16(T[c8 * 8 + i][n_l]);
      *(short8*)&WT[(size_t)(n0 + n_l) * K + k0 + c8 * 8] = *(short8*)ox;
    }
  }
}

// ---------------- epilogue helpers ----------------
__device__ __forceinline__ float softplus_f(float x) {
  return (x > 20.f) ? x : log1pf(__expf(x));
}
__device__ __forceinline__ float gelu_f(float x) {
  return 0.5f * x * (1.f + erff(x * 0.70710678118654752f));
}

// ---------------- MFMA GEMM 128x128 (ffn1, XCD-swizzled, T2-swizzled) ------
__global__ __launch_bounds__(256) void k_gemm_ffn1(
    const __hip_bfloat16* __restrict__ A, const __hip_bfloat16* __restrict__ BT,
    const float* __restrict__ bias, __hip_bfloat16* __restrict__ Cb) {
  __shared__ __align__(16) __hip_bfloat16 As[128 * 64];
  __shared__ __align__(16) __hip_bfloat16 Bs[128 * 64];
  const int tid = threadIdx.x;
  const int lane = tid & 63, wid = tid >> 6;
  int wg = (blockIdx.x & 7) * 48 + (blockIdx.x >> 3);   // 384 blocks, bijective
  int tn = wg % 24, tm = wg / 24;
  const int bm = tm * 128, bn = tn * 128;
  const int wm = wid >> 1, wn = wid & 1;
  const int sr = lane >> 3;
  const int sks = (((lane & 7) ^ (lane >> 3)) & 7) * 8;
  const int N = FF, K = DD;

  f32x4 acc[4][4] = {};

  for (int k0 = 0; k0 < K; k0 += 64) {
    __syncthreads();
    #pragma unroll
    for (int cc = 0; cc < 4; ++cc) {
      int ch = wid * 4 + cc;
      int row = ch * 8 + sr;
      g2l16(A  + (size_t)(bm + row) * K + k0 + sks, &As[ch * 512]);
      g2l16(BT + (size_t)(bn + row) * K + k0 + sks, &Bs[ch * 512]);
    }
    __syncthreads();
    #pragma unroll
    for (int kk = 0; kk < 2; ++kk) {
      int koff = (((kk * 4 + (lane >> 4)) ^ (lane & 7)) & 7) * 8;
      bf16x8 af[4], bfr[4];
      #pragma unroll
      for (int m = 0; m < 4; ++m)
        af[m] = *(const bf16x8*)&As[(wm * 64 + m * 16 + (lane & 15)) * 64 + koff];
      #pragma unroll
      for (int n = 0; n < 4; ++n)
        bfr[n] = *(const bf16x8*)&Bs[(wn * 64 + n * 16 + (lane & 15)) * 64 + koff];
      #pragma unroll
      for (int m = 0; m < 4; ++m)
        #pragma unroll
        for (int n = 0; n < 4; ++n)
          acc[m][n] = __builtin_amdgcn_mfma_f32_16x16x32_bf16(af[m], bfr[n], acc[m][n], 0, 0, 0);
    }
  }

  const int crow0 = (lane >> 4) * 4;
  const int ccol = lane & 15;
  #pragma unroll
  for (int m = 0; m < 4; ++m) {
    #pragma unroll
    for (int n = 0; n < 4; ++n) {
      int col = bn + wn * 64 + n * 16 + ccol;
      float bv = bias[col];
      #pragma unroll
      for (int j = 0; j < 4; ++j) {
        int row = bm + wm * 64 + m * 16 + crow0 + j;
        Cb[(size_t)row * N + col] = __float2bfloat16(gelu_f(acc[m][n][j] + bv));
      }
    }
  }
}

// ---------------- dt/B/C GEMM 64x64 (XCD-swizzled, T2-swizzled) ------------
__global__ __launch_bounds__(256) void k_gemm_dtbc64(
    const __hip_bfloat16* __restrict__ A, const __hip_bfloat16* __restrict__ BT,
    const float* __restrict__ dtbias, __hip_bfloat16* __restrict__ dtbb,
    float* __restrict__ Bm, float* __restrict__ Cm) {
  __shared__ __align__(16) __hip_bfloat16 As[64 * 64];
  __shared__ __align__(16) __hip_bfloat16 Bs[64 * 64];
  const int tid = threadIdx.x;
  const int lane = tid & 63, wid = tid >> 6;
  int wg = (blockIdx.x & 7) * 52 + (blockIdx.x >> 3);   // 416 blocks
  int tn = wg % 13, tm = wg / 13;
  const int bm = tm * 64, bn = tn * 64;
  const int wm = wid >> 1, wn = wid & 1;
  const int sr = lane >> 3;
  const int sks = (((lane & 7) ^ (lane >> 3)) & 7) * 8;

  f32x4 acc[2][2] = {};

  for (int k0 = 0; k0 < DD; k0 += 64) {
    __syncthreads();
    #pragma unroll
    for (int cc = 0; cc < 2; ++cc) {
      int ch = wid * 2 + cc;
      int row = ch * 8 + sr;
      g2l16(A  + (size_t)(bm + row) * DD + k0 + sks, &As[ch * 512]);
      g2l16(BT + (size_t)(bn + row) * DD + k0 + sks, &Bs[ch * 512]);
    }
    __syncthreads();
    #pragma unroll
    for (int kk = 0; kk < 2; ++kk) {
      int koff = (((kk * 4 + (lane >> 4)) ^ (lane & 7)) & 7) * 8;
      bf16x8 af[2], bfr[2];
      #pragma unroll
      for (int m = 0; m < 2; ++m)
        af[m] = *(const bf16x8*)&As[(wm * 32 + m * 16 + (lane & 15)) * 64 + koff];
      #pragma unroll
      for (int n = 0; n < 2; ++n)
        bfr[n] = *(const bf16x8*)&Bs[(wn * 32 + n * 16 + (lane & 15)) * 64 + koff];
      #pragma unroll
      for (int m = 0; m < 2; ++m)
        #pragma unroll
        for (int n = 0; n < 2; ++n)
          acc[m][n] = __builtin_amdgcn_mfma_f32_16x16x32_bf16(af[m], bfr[n], acc[m][n], 0, 0, 0);
    }
  }

  const int crow0 = (lane >> 4) * 4;
  const int ccol = lane & 15;
  #pragma unroll
  for (int m = 0; m < 2; ++m) {
    #pragma unroll
    for (int n = 0; n < 2; ++n) {
      int col = bn + wn * 32 + n * 16 + ccol;
      if (col >= 800) continue;
      float bv = (col < DD) ? dtbias[col] : 0.f;
      #pragma unroll
      for (int j = 0; j < 4; ++j) {
        int row = bm + wm * 32 + m * 16 + crow0 + j;
        float v = acc[m][n][j] + bv;
        if (col < DD)       dtbb[(size_t)row * DD + col] = __float2bfloat16(softplus_f(v));
        else if (col < 784) Bm[(size_t)row * NN + (col - DD)] = v;
        else                Cm[(size_t)row * NN + (col - 784)] = v;
      }
    }
  }
}

// ---------------- ffn2: 64x64 tiles, split-K=2, atomic epilogue ------------
__global__ __launch_bounds__(256) void k_gemm_ffn2s(
    const __hip_bfloat16* __restrict__ A, const __hip_bfloat16* __restrict__ BT,
    const float* __restrict__ bias, float* __restrict__ h) {
  __shared__ __align__(16) __hip_bfloat16 As[64 * 64];
  __shared__ __align__(16) __hip_bfloat16 Bs[64 * 64];
  const int tid = threadIdx.x;
  const int lane = tid & 63, wid = tid >> 6;
  int wg = (blockIdx.x & 7) * 96 + (blockIdx.x >> 3);   // 768 blocks
  int tile = wg % 384, split = wg / 384;
  int tm = tile % 32, tn = tile / 32;
  const int bm = tm * 64, bn = tn * 64;
  const int wm = wid >> 1, wn = wid & 1;
  const int sr = lane >> 3;
  const int sks = (((lane & 7) ^ (lane >> 3)) & 7) * 8;
  const int kbeg = split * (FF / 2), kend = kbeg + FF / 2;

  f32x4 acc[2][2] = {};

  for (int k0 = kbeg; k0 < kend; k0 += 64) {
    __syncthreads();
    #pragma unroll
    for (int cc = 0; cc < 2; ++cc) {
      int ch = wid * 2 + cc;
      int row = ch * 8 + sr;
      g2l16(A  + (size_t)(bm + row) * FF + k0 + sks, &As[ch * 512]);
      g2l16(BT + (size_t)(bn + row) * FF + k0 + sks, &Bs[ch * 512]);
    }
    __syncthreads();
    #pragma unroll
    for (int kk = 0; kk < 2; ++kk) {
      int koff = (((kk * 4 + (lane >> 4)) ^ (lane & 7)) & 7) * 8;
      bf16x8 af[2], bfr[2];
      #pragma unroll
      for (int m = 0; m < 2; ++m)
        af[m] = *(const bf16x8*)&As[(wm * 32 + m * 16 + (lane & 15)) * 64 + koff];
      #pragma unroll
      for (int n = 0; n < 2; ++n)
        bfr[n] = *(const bf16x8*)&Bs[(wn * 32 + n * 16 + (lane & 15)) * 64 + koff];
      #pragma unroll
      for (int m = 0; m < 2; ++m)
        #pragma unroll
        for (int n = 0; n < 2; ++n)
          acc[m][n] = __builtin_amdgcn_mfma_f32_16x16x32_bf16(af[m], bfr[n], acc[m][n], 0, 0, 0);
    }
  }

  const int crow0 = (lane >> 4) * 4;
  const int ccol = lane & 15;
  #pragma unroll
  for (int m = 0; m < 2; ++m) {
    #pragma unroll
    for (int n = 0; n < 2; ++n) {
      int col = bn + wn * 32 + n * 16 + ccol;
      float bv = (split == 0) ? bias[col] : 0.f;
      #pragma unroll
      for (int j = 0; j < 4; ++j) {
        int row = bm + wm * 32 + m * 16 + crow0 + j;
        unsafeAtomicAdd(&h[(size_t)row * DD + col], acc[m][n][j] + bv);
      }
    }
  }
}

// ---------------- Logits GEMM: BM=256, BN=128, 512 thr, T2 + LDS epilogue --
__global__ __launch_bounds__(512) void k_gemm_logits2(
    const __hip_bfloat16* __restrict__ A, const __hip_bfloat16* __restrict__ BT,
    const float* __restrict__ bias, float* __restrict__ C, int M, int N, int K) {
  __shared__ __align__(16) char smem[(256 * 64 + 128 * 64) * 2];  // 48 KB
  __hip_bfloat16* As = (__hip_bfloat16*)smem;
  __hip_bfloat16* Bs = (__hip_bfloat16*)(smem + 256 * 64 * 2);
  const int tid = threadIdx.x;
  const int lane = tid & 63, wid = tid >> 6;       // 8 waves
  int bid = blockIdx.y * gridDim.x + blockIdx.x;
  int mt = bid & 7, nt = bid >> 3;
  const int bm = mt * 256, bn = nt * 128;
  const int wm = wid >> 1, wn = wid & 1;
  const int sr = lane >> 3;
  const int sks = (((lane & 7) ^ (lane >> 3)) & 7) * 8;

  f32x4 acc[4][4] = {};

  for (int k0 = 0; k0 < K; k0 += 64) {
    __syncthreads();
    #pragma unroll
    for (int r = 0; r < 4; ++r) {
      int ch = r * 8 + wid;
      int row = ch * 8 + sr;
      g2l16(A + (size_t)(bm + row) * K + k0 + sks, &As[ch * 512]);
    }
    #pragma unroll
    for (int r = 0; r < 2; ++r) {
      int ch = r * 8 + wid;
      int row = ch * 8 + sr;
      g2l16(BT + (size_t)(bn + row) * K + k0 + sks, &Bs[ch * 512]);
    }
    __syncthreads();
    #pragma unroll
    for (int kk = 0; kk < 2; ++kk) {
      int koff = (((kk * 4 + (lane >> 4)) ^ (lane & 7)) & 7) * 8;
      bf16x8 af[4], bfr[4];
      #pragma unroll
      for (int m = 0; m < 4; ++m)
        af[m] = *(const bf16x8*)&As[(wm * 64 + m * 16 + (lane & 15)) * 64 + koff];
      #pragma unroll
      for (int n = 0; n < 4; ++n)
        bfr[n] = *(const bf16x8*)&Bs[(wn * 64 + n * 16 + (lane & 15)) * 64 + koff];
      #pragma unroll
      for (int m = 0; m < 4; ++m)
        #pragma unroll
        for (int n = 0; n < 4; ++n)
          acc[m][n] = __builtin_amdgcn_mfma_f32_16x16x32_bf16(af[m], bfr[n], acc[m][n], 0, 0, 0);
    }
  }

  // LDS-staged epilogue: full-cacheline C stores.
  __syncthreads();                      // all waves done reading As/Bs
  float* eps = (float*)smem + (size_t)wid * 1088;   // 16 x 68 f32 per wave
  const int crow0 = (lane >> 4) * 4;
  const int ccol = lane & 15;
  const int gcolbase = bn + wn * 64;
  #pragma unroll
  for (int m = 0; m < 4; ++m) {
    #pragma unroll
    for (int n = 0; n < 4; ++n) {
      float bv = bias[gcolbase + n * 16 + ccol];
      #pragma unroll
      for (int j = 0; j < 4; ++j)
        eps[(crow0 + j) * 68 + n * 16 + ccol] = acc[m][n][j] + bv;
    }
    int growbase = bm + wm * 64 + m * 16;
    #pragma unroll
    for (int p = 0; p < 2; ++p) {
      int r = (lane >> 3) + 8 * p;
      #pragma unroll
      for (int i = 0; i < 2; ++i) {
        int s4 = (lane & 7) + 8 * i;    // float4 slot 0..15
        float4 v = *(float4*)&eps[r * 68 + s4 * 4];
        *(float4*)&C[(size_t)(growbase + r) * N + gcolbase + s4 * 4] = v;
      }
    }
  }
}

// ---------------- fused selective scan (cooperative, 3 phases) --------------
// grid 384 x 256. Phase A: per-(chunk,d) local scan -> F(bf16),SD.
// Phase B: 4 wave-tasks/block = 1536 (b,d) wave-parallel prefixes (chunk=lane).
// Phase C: chunk recompute from Hinit, y into h (+optional hb).
// Math/layouts byte-identical to the proven 3-kernel path (rounds 11-13).
__global__ __launch_bounds__(256) void k_scan_fused(
    const __hip_bfloat16* __restrict__ dt, const __hip_bfloat16* __restrict__ ub,
    const float* __restrict__ Bm, const float* __restrict__ Cm,
    const float* __restrict__ A_log, const float* __restrict__ Dsk,
    __hip_bfloat16* __restrict__ F, float* __restrict__ SD,
    __hip_bfloat16* __restrict__ Hinit, float* __restrict__ hres,
    __hip_bfloat16* __restrict__ hb, int writeHb) {
  cg::grid_group grid = cg::this_grid();
  int blk = blockIdx.x;
  int tid = threadIdx.x;
  int c = blk & 63;          // chunk
  int seg = blk >> 6;        // 0..5
  int b = seg / 3;
  int d = (seg % 3) * 256 + tid;

  float Av[16];
  {
    const float4* al = (const float4*)(A_log + (size_t)d * NN);
    #pragma unroll
    for (int q = 0; q < 4; ++q) {
      float4 v = al[q];
      Av[q * 4 + 0] = -__expf(v.x);
      Av[q * 4 + 1] = -__expf(v.y);
      Av[q * 4 + 2] = -__expf(v.z);
      Av[q * 4 + 3] = -__expf(v.w);
    }
  }

  // ---- Phase A ----
  {
    float hA[16];
    #pragma unroll
    for (int n = 0; n < 16; ++n) hA[n] = 0.f;
    float sdt = 0.f;
    size_t base = ((size_t)b * LL + (size_t)c * CLEN) * DD + d;
    int row0 = c * CLEN + b * LL;
    #pragma unroll 4
    for (int t = 0; t < CLEN; ++t) {
      float dtv = __bfloat162float(dt[base + (size_t)t * DD]);
      float uv  = __bfloat162float(ub[base + (size_t)t * DD]);
      float Bv[16];
      const float4* bp = (const float4*)(Bm + (size_t)(row0 + t) * NN);
      *(float4*)&Bv[0]  = bp[0];
      *(float4*)&Bv[4]  = bp[1];
      *(float4*)&Bv[8]  = bp[2];
      *(float4*)&Bv[12] = bp[3];
      float du = dtv * uv;
      sdt += dtv;
      #pragma unroll
      for (int n = 0; n < 16; ++n)
        hA[n] = __expf(dtv * Av[n]) * hA[n] + du * Bv[n];
    }
    alignas(16) __hip_bfloat16 fx[16];
    #pragma unroll
    for (int n = 0; n < 16; ++n) fx[n] = __float2bfloat16(hA[n]);
    __hip_bfloat16* fo = F + (((size_t)c * BB + b) * DD + d) * NN;
    *(short8*)&fo[0] = *(short8*)&fx[0];
    *(short8*)&fo[8] = *(short8*)&fx[8];
    SD[((size_t)c * BB + b) * DD + d] = sdt;
  }

  __threadfence();     // make F/SD visible device-wide before the grid barrier
  grid.sync();

  // ---- Phase B: wave-parallel affine prefix (chunk = lane) ----
  {
    int w = tid >> 6, lane = tid & 63;
    int task = blk * 4 + w;               // [0,1536) = b2*DD + d2
    int b2 = task / DD, d2 = task - b2 * DD;
    float Av2[16];
    {
      const float4* al = (const float4*)(A_log + (size_t)d2 * NN);
      #pragma unroll
      for (int q = 0; q < 4; ++q) {
        float4 v = al[q];
        Av2[q * 4 + 0] = -__expf(v.x);
        Av2[q * 4 + 1] = -__expf(v.y);
        Av2[q * 4 + 2] = -__expf(v.z);
        Av2[q * 4 + 3] = -__expf(v.w);
      }
    }
    float sd = SD[((size_t)lane * BB + b2) * DD + d2];
    float Fr[16], Hr[16];
    {
      alignas(16) __hip_bfloat16 fx[16];
      const __hip_bfloat16* fp = F + (((size_t)lane * BB + b2) * DD + d2) * NN;
      *(short8*)&fx[0] = *(const short8*)&fp[0];
      *(short8*)&fx[8] = *(const short8*)&fp[8];
      #pragma unroll
      for (int n = 0; n < 16; ++n) Fr[n] = __bfloat162float(fx[n]);
    }
    #pragma unroll
    for (int n = 0; n < 16; ++n) {
      float Fv = Fr[n];
      float Dv = __expf(sd * Av2[n]);
      #pragma unroll
      for (int s = 1; s < 64; s <<= 1) {
        float Fp = __shfl_up(Fv, s);
        float Dp = __shfl_up(Dv, s);
        float nF = Fv + Dv * Fp;
        float nD = Dv * Dp;
        Fv = (lane >= s) ? nF : Fv;
        Dv = (lane >= s) ? nD : Dv;
      }
      float Hi = __shfl_up(Fv, 1);
      Hr[n] = (lane == 0) ? 0.f : Hi;
    }
    {
      alignas(16) __hip_bfloat16 hx[16];
      #pragma unroll
      for (int n = 0; n < 16; ++n) hx[n] = __float2bfloat16(Hr[n]);
      __hip_bfloat16* hp = Hinit + (((size_t)lane * BB + b2) * DD + d2) * NN;
      *(short8*)&hp[0] = *(short8*)&hx[0];
      *(short8*)&hp[8] = *(short8*)&hx[8];
    }
  }

  __threadfence();     // make Hinit visible device-wide before the grid barrier
  grid.sync();

  // ---- Phase C ----
  {
    float hC[16];
    {
      alignas(16) __hip_bfloat16 hx[16];
      const __hip_bfloat16* hi = Hinit + (((size_t)c * BB + b) * DD + d) * NN;
      *(short8*)&hx[0] = *(const short8*)&hi[0];
      *(short8*)&hx[8] = *(const short8*)&hi[8];
      #pragma unroll
      for (int n = 0; n < 16; ++n) hC[n] = __bfloat162float(hx[n]);
    }
    float dskip = Dsk[d];
    size_t base = ((size_t)b * LL + (size_t)c * CLEN) * DD + d;
    int row0 = c * CLEN + b * LL;
    #pragma unroll 4
    for (int t = 0; t < CLEN; ++t) {
      float dtv = __bfloat162float(dt[base + (size_t)t * DD]);
      float uv  = __bfloat162float(ub[base + (size_t)t * DD]);
      float Bv[16], Cv[16];
      const float4* bp = (const float4*)(Bm + (size_t)(row0 + t) * NN);
      const float4* cp = (const float4*)(Cm + (size_t)(row0 + t) * NN);
      *(float4*)&Bv[0]  = bp[0];
      *(float4*)&Bv[4]  = bp[1];
      *(float4*)&Bv[8]  = bp[2];
      *(float4*)&Bv[12] = bp[3];
      *(float4*)&Cv[0]  = cp[0];
      *(float4*)&Cv[4]  = cp[1];
      *(float4*)&Cv[8]  = cp[2];
      *(float4*)&Cv[12] = cp[3];
      float du = dtv * uv;
      float y = 0.f;
      #pragma unroll
      for (int n = 0; n < 16; ++n) {
        hC[n] = __expf(dtv * Av[n]) * hC[n] + du * Bv[n];
        y += hC[n] * Cv[n];
      }
      float nh = hres[base + (size_t)t * DD] + y + dskip * uv;
      hres[base + (size_t)t * DD] = nh;
      if (writeHb) hb[base + (size_t)t * DD] = __float2bfloat16(nh);
    }
  }
}

// ---------------- launch ----------------
extern "C" void kernel_launch(void* const* d_in, const int* in_sizes, int n_in,
                              void* d_out, int out_size, void* d_ws, size_t ws_size,
                              hipStream_t stream) {
  const int*   x     = (const int*)d_in[0];
  const float* emb   = (const float*)d_in[1];
  const float* convw = (const float*)d_in[2];
  const float* A_log = (const float*)d_in[3];
  const float* W_B   = (const float*)d_in[4];
  const float* W_C   = (const float*)d_in[5];
  const float* W_dt  = (const float*)d_in[6];
  const float* dt_b  = (const float*)d_in[7];
  const float* D_sk  = (const float*)d_in[8];
  const float* W1    = (const float*)d_in[9];
  const float* b1    = (const float*)d_in[10];
  const float* W2    = (const float*)d_in[11];
  const float* b2    = (const float*)d_in[12];
  const float* ng    = (const float*)d_in[13];
  const float* nb    = (const float*)d_in[14];
  const float* Wout  = (const float*)d_in[15];
  const float* bout  = (const float*)d_in[16];
  float* out = (float*)d_out;

  // converted dt/FFN weights live in d_out (dead until logits writes it)
  __hip_bfloat16* WTdt = (__hip_bfloat16*)d_out;            // 12*832*768
  __hip_bfloat16* WT1  = WTdt + (size_t)12 * 832 * DD;      // 4*3072*768
  __hip_bfloat16* WT2  = WT1  + (size_t)NLL * FF * DD;      // 4*768*3072
  // ends at ~53 MB < 262 MB out buffer

  char* p = (char*)d_ws;
  auto alloc = [&](size_t bytes) { char* r = p; p += (bytes + 255) & ~(size_t)255; return r; };
  float* h    = (float*)alloc((size_t)BL * DD * 4);
  float* Bm   = (float*)alloc((size_t)BL * NN * 4);
  float* Cm   = (float*)alloc((size_t)BL * NN * 4);
  float* SD   = (float*)alloc((size_t)CHK * BB * DD * 4);
  __hip_bfloat16* dtbb  = (__hip_bfloat16*)alloc((size_t)BL * DD * 2);
  __hip_bfloat16* F     = (__hip_bfloat16*)alloc((size_t)CHK * BB * DD * NN * 2);
  __hip_bfloat16* Hini  = (__hip_bfloat16*)alloc((size_t)CHK * BB * DD * NN * 2);
  __hip_bfloat16* ub    = (__hip_bfloat16*)alloc((size_t)BL * DD * 2);
  __hip_bfloat16* hb    = (__hip_bfloat16*)alloc((size_t)BL * DD * 2);
  __hip_bfloat16* fb    = (__hip_bfloat16*)alloc((size_t)BL * FF * 2);
  __hip_bfloat16* lnb   = (__hip_bfloat16*)alloc((size_t)BL * DD * 2);
  __hip_bfloat16* WTlog = (__hip_bfloat16*)alloc((size_t)VV * DD * 2);

  k_wconv_all<<<SEND, 256, 0, stream>>>(
      W_dt, W_B, W_C, W1, W2, Wout, WTdt, WT1, WT2, WTlog);
  k_embed<<<1536, 256, 0, stream>>>(x, emb, h);

  for (int l = 0; l < NLL; ++l) {
    for (int s = 0; s < NSS; ++s) {
      int ls = l * NSS + s;
      k_conv<<<1536, 256, 0, stream>>>(h, convw + (size_t)ls * DD * 3, ub);
      k_gemm_dtbc64<<<416, 256, 0, stream>>>(
          ub, WTdt + (size_t)ls * 832 * DD, dt_b + (size_t)ls * DD, dtbb, Bm, Cm);
      {
        const __hip_bfloat16* dt_p = dtbb;
        const __hip_bfloat16* ub_p = ub;
        const float* Bm_p   = Bm;
        const float* Cm_p   = Cm;
        const float* alog_p = A_log + (size_t)ls * DD * NN;
        const float* dsk_p  = D_sk + (size_t)ls * DD;
        __hip_bfloat16* F_p = F; float* SD_p = SD;
        __hip_bfloat16* Hi_p = Hini;
        float* h_p = h; __hip_bfloat16* hb_p = hb;
        int wHb = (s == NSS - 1) ? 1 : 0;
        void* args[] = {
          (void*)&dt_p, (void*)&ub_p, (void*)&Bm_p, (void*)&Cm_p,
          (void*)&alog_p, (void*)&dsk_p, (void*)&F_p, (void*)&SD_p,
          (void*)&Hi_p, (void*)&h_p, (void*)&hb_p, (void*)&wHb};
        hipLaunchCooperativeKernel((void*)k_scan_fused, dim3(CHK * 6), dim3(256),
                                   args, 0, stream);
      }
    }
    k_gemm_ffn1<<<384, 256, 0, stream>>>(
        hb, WT1 + (size_t)l * FF * DD, b1 + (size_t)l * FF, fb);
    k_gemm_ffn2s<<<768, 256, 0, stream>>>(
        fb, WT2 + (size_t)l * DD * FF, b2 + (size_t)l * DD, h);
  }

  k_layernorm<<<BL, 256, 0, stream>>>(h, ng, nb, lnb);
  k_gemm_logits2<<<dim3(VV / 128, BL / 256), 512, 0, stream>>>(
      lnb, WTlog, bout, out, BL, VV, DD);
}

// Round 15
// 1116.536 us; speedup vs baseline: 3.0171x; 3.0171x over previous
//
#include <hip/hip_runtime.h>
#include <hip/hip_bf16.h>
#include <math.h>

// Problem constants
#define BB 2
#define LL 1024
#define DD 768
#define NN 16
#define FF 3072
#define VV 32000
#define NLL 4
#define NSS 3
#define BL (BB*LL)    // 2048
#define CHK 64        // scan chunks
#define CLEN (LL/CHK) // 16

typedef __bf16 bf16x8 __attribute__((ext_vector_type(8)));
typedef float f32x4 __attribute__((ext_vector_type(4)));
typedef short short8 __attribute__((ext_vector_type(8)));
typedef short short4v __attribute__((ext_vector_type(4)));

typedef __attribute__((address_space(1))) const void gconst_t;
typedef __attribute__((address_space(3))) void lds_t;

__device__ __forceinline__ void g2l16(const void* g, void* l) {
  __builtin_amdgcn_global_load_lds((gconst_t*)g, (lds_t*)l, 16, 0, 0);
}

// T2 XOR-swizzle (rule #21): LDS linear; global SOURCE pre-swizzled;
// read XORs the same involution. stage: ((lane&7)^(lane>>3))*8
// read: ((kk*4+(lane>>4))^(lane&7))*8
// NOTE (session finding): cooperative grid.sync() costs ~100us/barrier on
// MI355X (8 non-coherent XCD L2s) — kernel-boundary sync is strictly cheaper.

// ---------------- elementwise kernels ----------------

// embed, float4-vectorized: grid 1536 x 256 (one float4 per thread).
__global__ __launch_bounds__(256) void k_embed(
    const int* __restrict__ x, const float* __restrict__ emb,
    float* __restrict__ h) {
  int gid = blockIdx.x * 256 + threadIdx.x;   // 0..393215
  int row = gid / 192;
  int g = (gid - row * 192) * 4;
  int idx = x[row];
  *(float4*)&h[(size_t)row * DD + g] =
      *(const float4*)&emb[(size_t)idx * DD + g];
}

// conv + silu -> ub (bf16), float4-vectorized. grid 1536 x 256.
__global__ __launch_bounds__(256) void k_conv(
    const float* __restrict__ h, const float* __restrict__ cw,
    __hip_bfloat16* __restrict__ ub) {
  int gid = blockIdx.x * 256 + threadIdx.x;   // 0..393215
  int row = gid / 192;
  int g = gid - row * 192;
  int d0 = g * 4;
  int l = row & (LL - 1);
  float4 h0 = *(const float4*)&h[(size_t)row * DD + d0];
  float4 h1, h2;
  if (l >= 1) h1 = *(const float4*)&h[(size_t)(row - 1) * DD + d0];
  else { h1.x = h1.y = h1.z = h1.w = 0.f; }
  if (l >= 2) h2 = *(const float4*)&h[(size_t)(row - 2) * DD + d0];
  else { h2.x = h2.y = h2.z = h2.w = 0.f; }
  const float* hp0 = (const float*)&h0;
  const float* hp1 = (const float*)&h1;
  const float* hp2 = (const float*)&h2;
  alignas(8) __hip_bfloat16 o[4];
  #pragma unroll
  for (int i = 0; i < 4; ++i) {
    int d = d0 + i;
    float v = hp2[i] * cw[d * 3 + 0] + hp1[i] * cw[d * 3 + 1] + hp0[i] * cw[d * 3 + 2];
    float sv = v / (1.f + __expf(-v));
    o[i] = __float2bfloat16(sv);
  }
  *(short4v*)&ub[(size_t)row * DD + d0] = *(short4v*)o;
}

__global__ __launch_bounds__(256) void k_layernorm(
    const float* __restrict__ x, const float* __restrict__ g,
    const float* __restrict__ bta, __hip_bfloat16* __restrict__ o) {
  int row = blockIdx.x;
  const float* xr = x + (size_t)row * DD;
  int tid = threadIdx.x;
  float v1 = xr[tid], v2 = xr[tid + 256], v3 = xr[tid + 512];
  float s = v1 + v2 + v3;
  float sq = v1 * v1 + v2 * v2 + v3 * v3;
  #pragma unroll
  for (int m = 1; m < 64; m <<= 1) {
    s  += __shfl_xor(s, m);
    sq += __shfl_xor(sq, m);
  }
  __shared__ float ss[4], sqs[4];
  if ((tid & 63) == 0) { ss[tid >> 6] = s; sqs[tid >> 6] = sq; }
  __syncthreads();
  s  = ss[0] + ss[1] + ss[2] + ss[3];
  sq = sqs[0] + sqs[1] + sqs[2] + sqs[3];
  float mean = s * (1.f / DD);
  float var  = sq * (1.f / DD) - mean * mean;
  float rstd = rsqrtf(var + 1e-5f);
  o[(size_t)row * DD + tid]       = __float2bfloat16((v1 - mean) * rstd * g[tid]       + bta[tid]);
  o[(size_t)row * DD + tid + 256] = __float2bfloat16((v2 - mean) * rstd * g[tid + 256] + bta[tid + 256]);
  o[(size_t)row * DD + tid + 512] = __float2bfloat16((v3 - mean) * rstd * g[tid + 512] + bta[tid + 512]);
}

// ---------------- batched weight convert+transpose (vectorized) -------------
#define S1 1728
#define S2 1740
#define S3 4044
#define S4 6348
#define SEND 12348

__global__ __launch_bounds__(256) void k_wconv_all(
    const float* __restrict__ Wdt, const float* __restrict__ WB,
    const float* __restrict__ WC, const float* __restrict__ W1,
    const float* __restrict__ W2, const float* __restrict__ Wout,
    __hip_bfloat16* __restrict__ WTdt, __hip_bfloat16* __restrict__ WT1,
    __hip_bfloat16* __restrict__ WT2, __hip_bfloat16* __restrict__ WTlog) {
  __shared__ float T[64][65];
  int bid = blockIdx.x;
  int tid = threadIdx.x;

  if (bid >= S1 && bid < S2) {   // B/C strips
    int sub = bid - S1;
    const float* WBp = WB + (size_t)sub * DD * NN;
    const float* WCp = WC + (size_t)sub * DD * NN;
    __hip_bfloat16* dst = WTdt + (size_t)sub * 832 * DD;
    for (int e = tid; e < 64 * DD; e += 256) {
      int r = e / DD, k = e - (e / DD) * DD;
      float v = 0.f;
      if (r < 16)      v = WBp[(size_t)k * NN + r];
      else if (r < 32) v = WCp[(size_t)k * NN + (r - 16)];
      dst[(size_t)(768 + r) * DD + k] = __float2bfloat16(v);
    }
    return;
  }

  const float* W; __hip_bfloat16* WT;
  int K, N, n0, k0;
  if (bid < S1) {
    int sub = bid / 144, t = bid % 144;
    W = Wdt + (size_t)sub * DD * DD; WT = WTdt + (size_t)sub * 832 * DD;
    K = DD; N = DD; n0 = (t % 12) * 64; k0 = (t / 12) * 64;
  } else if (bid < S3) {
    int idx = bid - S2, l = idx / 576, t = idx % 576;
    W = W1 + (size_t)l * DD * FF; WT = WT1 + (size_t)l * FF * DD;
    K = DD; N = FF; n0 = (t % 48) * 64; k0 = (t / 48) * 64;
  } else if (bid < S4) {
    int idx = bid - S3, l = idx / 576, t = idx % 576;
    W = W2 + (size_t)l * FF * DD; WT = WT2 + (size_t)l * DD * FF;
    K = FF; N = DD; n0 = (t % 12) * 64; k0 = (t / 12) * 64;
  } else {
    int t = bid - S4;
    W = Wout; WT = WTlog;
    K = DD; N = VV; n0 = (t % 500) * 64; k0 = (t / 500) * 64;
  }

  // load: float4 per lane (16 B)
  {
    int r0 = tid >> 4, c4 = (tid & 15) * 4;
    #pragma unroll
    for (int i = 0; i < 4; ++i) {
      int r = r0 + 16 * i;
      float4 v = *(const float4*)&W[(size_t)(k0 + r) * N + n0 + c4];
      T[r][c4 + 0] = v.x;
      T[r][c4 + 1] = v.y;
      T[r][c4 + 2] = v.z;
      T[r][c4 + 3] = v.w;
    }
  }
  __syncthreads();
  // store: bf16x8 per lane (16 B), 8 lanes cover one 64-col row
  {
    int c8 = tid & 7;
    #pragma unroll
    for (int j = 0; j < 2; ++j) {
      int n_l = (tid >> 3) + 32 * j;
      alignas(16) __hip_bfloat16 ox[8];
      #pragma unroll
      for (int i = 0; i < 8; ++i)
        ox[i] = __float2bfloat16(T[c8 * 8 + i][n_l]);
      *(short8*)&WT[(size_t)(n0 + n_l) * K + k0 + c8 * 8] = *(short8*)ox;
    }
  }
}

// ---------------- epilogue helpers ----------------
__device__ __forceinline__ float softplus_f(float x) {
  return (x > 20.f) ? x : log1pf(__expf(x));
}
__device__ __forceinline__ float gelu_f(float x) {
  return 0.5f * x * (1.f + erff(x * 0.70710678118654752f));
}

// ---------------- MFMA GEMM 128x128 (ffn1, XCD-swizzled, T2-swizzled) ------
__global__ __launch_bounds__(256) void k_gemm_ffn1(
    const __hip_bfloat16* __restrict__ A, const __hip_bfloat16* __restrict__ BT,
    const float* __restrict__ bias, __hip_bfloat16* __restrict__ Cb) {
  __shared__ __align__(16) __hip_bfloat16 As[128 * 64];
  __shared__ __align__(16) __hip_bfloat16 Bs[128 * 64];
  const int tid = threadIdx.x;
  const int lane = tid & 63, wid = tid >> 6;
  int wg = (blockIdx.x & 7) * 48 + (blockIdx.x >> 3);   // 384 blocks, bijective
  int tn = wg % 24, tm = wg / 24;
  const int bm = tm * 128, bn = tn * 128;
  const int wm = wid >> 1, wn = wid & 1;
  const int sr = lane >> 3;
  const int sks = (((lane & 7) ^ (lane >> 3)) & 7) * 8;
  const int N = FF, K = DD;

  f32x4 acc[4][4] = {};

  for (int k0 = 0; k0 < K; k0 += 64) {
    __syncthreads();
    #pragma unroll
    for (int cc = 0; cc < 4; ++cc) {
      int ch = wid * 4 + cc;
      int row = ch * 8 + sr;
      g2l16(A  + (size_t)(bm + row) * K + k0 + sks, &As[ch * 512]);
      g2l16(BT + (size_t)(bn + row) * K + k0 + sks, &Bs[ch * 512]);
    }
    __syncthreads();
    #pragma unroll
    for (int kk = 0; kk < 2; ++kk) {
      int koff = (((kk * 4 + (lane >> 4)) ^ (lane & 7)) & 7) * 8;
      bf16x8 af[4], bfr[4];
      #pragma unroll
      for (int m = 0; m < 4; ++m)
        af[m] = *(const bf16x8*)&As[(wm * 64 + m * 16 + (lane & 15)) * 64 + koff];
      #pragma unroll
      for (int n = 0; n < 4; ++n)
        bfr[n] = *(const bf16x8*)&Bs[(wn * 64 + n * 16 + (lane & 15)) * 64 + koff];
      #pragma unroll
      for (int m = 0; m < 4; ++m)
        #pragma unroll
        for (int n = 0; n < 4; ++n)
          acc[m][n] = __builtin_amdgcn_mfma_f32_16x16x32_bf16(af[m], bfr[n], acc[m][n], 0, 0, 0);
    }
  }

  const int crow0 = (lane >> 4) * 4;
  const int ccol = lane & 15;
  #pragma unroll
  for (int m = 0; m < 4; ++m) {
    #pragma unroll
    for (int n = 0; n < 4; ++n) {
      int col = bn + wn * 64 + n * 16 + ccol;
      float bv = bias[col];
      #pragma unroll
      for (int j = 0; j < 4; ++j) {
        int row = bm + wm * 64 + m * 16 + crow0 + j;
        Cb[(size_t)row * N + col] = __float2bfloat16(gelu_f(acc[m][n][j] + bv));
      }
    }
  }
}

// ---------------- dt/B/C GEMM 64x64 (XCD-swizzled, T2-swizzled) ------------
__global__ __launch_bounds__(256) void k_gemm_dtbc64(
    const __hip_bfloat16* __restrict__ A, const __hip_bfloat16* __restrict__ BT,
    const float* __restrict__ dtbias, __hip_bfloat16* __restrict__ dtbb,
    float* __restrict__ Bm, float* __restrict__ Cm) {
  __shared__ __align__(16) __hip_bfloat16 As[64 * 64];
  __shared__ __align__(16) __hip_bfloat16 Bs[64 * 64];
  const int tid = threadIdx.x;
  const int lane = tid & 63, wid = tid >> 6;
  int wg = (blockIdx.x & 7) * 52 + (blockIdx.x >> 3);   // 416 blocks
  int tn = wg % 13, tm = wg / 13;
  const int bm = tm * 64, bn = tn * 64;
  const int wm = wid >> 1, wn = wid & 1;
  const int sr = lane >> 3;
  const int sks = (((lane & 7) ^ (lane >> 3)) & 7) * 8;

  f32x4 acc[2][2] = {};

  for (int k0 = 0; k0 < DD; k0 += 64) {
    __syncthreads();
    #pragma unroll
    for (int cc = 0; cc < 2; ++cc) {
      int ch = wid * 2 + cc;
      int row = ch * 8 + sr;
      g2l16(A  + (size_t)(bm + row) * DD + k0 + sks, &As[ch * 512]);
      g2l16(BT + (size_t)(bn + row) * DD + k0 + sks, &Bs[ch * 512]);
    }
    __syncthreads();
    #pragma unroll
    for (int kk = 0; kk < 2; ++kk) {
      int koff = (((kk * 4 + (lane >> 4)) ^ (lane & 7)) & 7) * 8;
      bf16x8 af[2], bfr[2];
      #pragma unroll
      for (int m = 0; m < 2; ++m)
        af[m] = *(const bf16x8*)&As[(wm * 32 + m * 16 + (lane & 15)) * 64 + koff];
      #pragma unroll
      for (int n = 0; n < 2; ++n)
        bfr[n] = *(const bf16x8*)&Bs[(wn * 32 + n * 16 + (lane & 15)) * 64 + koff];
      #pragma unroll
      for (int m = 0; m < 2; ++m)
        #pragma unroll
        for (int n = 0; n < 2; ++n)
          acc[m][n] = __builtin_amdgcn_mfma_f32_16x16x32_bf16(af[m], bfr[n], acc[m][n], 0, 0, 0);
    }
  }

  const int crow0 = (lane >> 4) * 4;
  const int ccol = lane & 15;
  #pragma unroll
  for (int m = 0; m < 2; ++m) {
    #pragma unroll
    for (int n = 0; n < 2; ++n) {
      int col = bn + wn * 32 + n * 16 + ccol;
      if (col >= 800) continue;
      float bv = (col < DD) ? dtbias[col] : 0.f;
      #pragma unroll
      for (int j = 0; j < 4; ++j) {
        int row = bm + wm * 32 + m * 16 + crow0 + j;
        float v = acc[m][n][j] + bv;
        if (col < DD)       dtbb[(size_t)row * DD + col] = __float2bfloat16(softplus_f(v));
        else if (col < 784) Bm[(size_t)row * NN + (col - DD)] = v;
        else                Cm[(size_t)row * NN + (col - 784)] = v;
      }
    }
  }
}

// ---------------- ffn2: 64x64 tiles, split-K=2, atomic epilogue ------------
__global__ __launch_bounds__(256) void k_gemm_ffn2s(
    const __hip_bfloat16* __restrict__ A, const __hip_bfloat16* __restrict__ BT,
    const float* __restrict__ bias, float* __restrict__ h) {
  __shared__ __align__(16) __hip_bfloat16 As[64 * 64];
  __shared__ __align__(16) __hip_bfloat16 Bs[64 * 64];
  const int tid = threadIdx.x;
  const int lane = tid & 63, wid = tid >> 6;
  int wg = (blockIdx.x & 7) * 96 + (blockIdx.x >> 3);   // 768 blocks
  int tile = wg % 384, split = wg / 384;
  int tm = tile % 32, tn = tile / 32;
  const int bm = tm * 64, bn = tn * 64;
  const int wm = wid >> 1, wn = wid & 1;
  const int sr = lane >> 3;
  const int sks = (((lane & 7) ^ (lane >> 3)) & 7) * 8;
  const int kbeg = split * (FF / 2), kend = kbeg + FF / 2;

  f32x4 acc[2][2] = {};

  for (int k0 = kbeg; k0 < kend; k0 += 64) {
    __syncthreads();
    #pragma unroll
    for (int cc = 0; cc < 2; ++cc) {
      int ch = wid * 2 + cc;
      int row = ch * 8 + sr;
      g2l16(A  + (size_t)(bm + row) * FF + k0 + sks, &As[ch * 512]);
      g2l16(BT + (size_t)(bn + row) * FF + k0 + sks, &Bs[ch * 512]);
    }
    __syncthreads();
    #pragma unroll
    for (int kk = 0; kk < 2; ++kk) {
      int koff = (((kk * 4 + (lane >> 4)) ^ (lane & 7)) & 7) * 8;
      bf16x8 af[2], bfr[2];
      #pragma unroll
      for (int m = 0; m < 2; ++m)
        af[m] = *(const bf16x8*)&As[(wm * 32 + m * 16 + (lane & 15)) * 64 + koff];
      #pragma unroll
      for (int n = 0; n < 2; ++n)
        bfr[n] = *(const bf16x8*)&Bs[(wn * 32 + n * 16 + (lane & 15)) * 64 + koff];
      #pragma unroll
      for (int m = 0; m < 2; ++m)
        #pragma unroll
        for (int n = 0; n < 2; ++n)
          acc[m][n] = __builtin_amdgcn_mfma_f32_16x16x32_bf16(af[m], bfr[n], acc[m][n], 0, 0, 0);
    }
  }

  const int crow0 = (lane >> 4) * 4;
  const int ccol = lane & 15;
  #pragma unroll
  for (int m = 0; m < 2; ++m) {
    #pragma unroll
    for (int n = 0; n < 2; ++n) {
      int col = bn + wn * 32 + n * 16 + ccol;
      float bv = (split == 0) ? bias[col] : 0.f;
      #pragma unroll
      for (int j = 0; j < 4; ++j) {
        int row = bm + wm * 32 + m * 16 + crow0 + j;
        unsafeAtomicAdd(&h[(size_t)row * DD + col], acc[m][n][j] + bv);
      }
    }
  }
}

// ---------------- Logits GEMM: BM=256, BN=128, 512 thr, T2 + LDS epilogue --
__global__ __launch_bounds__(512) void k_gemm_logits2(
    const __hip_bfloat16* __restrict__ A, const __hip_bfloat16* __restrict__ BT,
    const float* __restrict__ bias, float* __restrict__ C, int M, int N, int K) {
  __shared__ __align__(16) char smem[(256 * 64 + 128 * 64) * 2];  // 48 KB
  __hip_bfloat16* As = (__hip_bfloat16*)smem;
  __hip_bfloat16* Bs = (__hip_bfloat16*)(smem + 256 * 64 * 2);
  const int tid = threadIdx.x;
  const int lane = tid & 63, wid = tid >> 6;       // 8 waves
  int bid = blockIdx.y * gridDim.x + blockIdx.x;
  int mt = bid & 7, nt = bid >> 3;
  const int bm = mt * 256, bn = nt * 128;
  const int wm = wid >> 1, wn = wid & 1;
  const int sr = lane >> 3;
  const int sks = (((lane & 7) ^ (lane >> 3)) & 7) * 8;

  f32x4 acc[4][4] = {};

  for (int k0 = 0; k0 < K; k0 += 64) {
    __syncthreads();
    #pragma unroll
    for (int r = 0; r < 4; ++r) {
      int ch = r * 8 + wid;
      int row = ch * 8 + sr;
      g2l16(A + (size_t)(bm + row) * K + k0 + sks, &As[ch * 512]);
    }
    #pragma unroll
    for (int r = 0; r < 2; ++r) {
      int ch = r * 8 + wid;
      int row = ch * 8 + sr;
      g2l16(BT + (size_t)(bn + row) * K + k0 + sks, &Bs[ch * 512]);
    }
    __syncthreads();
    #pragma unroll
    for (int kk = 0; kk < 2; ++kk) {
      int koff = (((kk * 4 + (lane >> 4)) ^ (lane & 7)) & 7) * 8;
      bf16x8 af[4], bfr[4];
      #pragma unroll
      for (int m = 0; m < 4; ++m)
        af[m] = *(const bf16x8*)&As[(wm * 64 + m * 16 + (lane & 15)) * 64 + koff];
      #pragma unroll
      for (int n = 0; n < 4; ++n)
        bfr[n] = *(const bf16x8*)&Bs[(wn * 64 + n * 16 + (lane & 15)) * 64 + koff];
      #pragma unroll
      for (int m = 0; m < 4; ++m)
        #pragma unroll
        for (int n = 0; n < 4; ++n)
          acc[m][n] = __builtin_amdgcn_mfma_f32_16x16x32_bf16(af[m], bfr[n], acc[m][n], 0, 0, 0);
    }
  }

  // LDS-staged epilogue: full-cacheline C stores.
  __syncthreads();                      // all waves done reading As/Bs
  float* eps = (float*)smem + (size_t)wid * 1088;   // 16 x 68 f32 per wave
  const int crow0 = (lane >> 4) * 4;
  const int ccol = lane & 15;
  const int gcolbase = bn + wn * 64;
  #pragma unroll
  for (int m = 0; m < 4; ++m) {
    #pragma unroll
    for (int n = 0; n < 4; ++n) {
      float bv = bias[gcolbase + n * 16 + ccol];
      #pragma unroll
      for (int j = 0; j < 4; ++j)
        eps[(crow0 + j) * 68 + n * 16 + ccol] = acc[m][n][j] + bv;
    }
    int growbase = bm + wm * 64 + m * 16;
    #pragma unroll
    for (int p = 0; p < 2; ++p) {
      int r = (lane >> 3) + 8 * p;
      #pragma unroll
      for (int i = 0; i < 2; ++i) {
        int s4 = (lane & 7) + 8 * i;    // float4 slot 0..15
        float4 v = *(float4*)&eps[r * 68 + s4 * 4];
        *(float4*)&C[(size_t)(growbase + r) * N + gcolbase + s4 * 4] = v;
      }
    }
  }
}

// ---------------- chunked selective scan (3 kernels, bf16 interfaces) -------
__global__ __launch_bounds__(256) void k_scan_a(
    const __hip_bfloat16* __restrict__ dt, const __hip_bfloat16* __restrict__ ub,
    const float* __restrict__ Bm, const float* __restrict__ A_log,
    __hip_bfloat16* __restrict__ F, float* __restrict__ SD) {
  int c = blockIdx.x;
  int bd = blockIdx.y;
  int b = bd / 3;
  int d = (bd % 3) * 256 + threadIdx.x;
  float Av[16];
  {
    const float4* al = (const float4*)(A_log + (size_t)d * NN);
    #pragma unroll
    for (int q = 0; q < 4; ++q) {
      float4 v = al[q];
      Av[q * 4 + 0] = -__expf(v.x);
      Av[q * 4 + 1] = -__expf(v.y);
      Av[q * 4 + 2] = -__expf(v.z);
      Av[q * 4 + 3] = -__expf(v.w);
    }
  }
  float h[16];
  #pragma unroll
  for (int n = 0; n < 16; ++n) h[n] = 0.f;
  float sdt = 0.f;
  size_t base = ((size_t)b * LL + (size_t)c * CLEN) * DD + d;
  int row0 = c * CLEN + b * LL;
  #pragma unroll 4
  for (int t = 0; t < CLEN; ++t) {
    float dtv = __bfloat162float(dt[base + (size_t)t * DD]);
    float uv  = __bfloat162float(ub[base + (size_t)t * DD]);
    float Bv[16];
    const float4* bp = (const float4*)(Bm + (size_t)(row0 + t) * NN);
    *(float4*)&Bv[0]  = bp[0];
    *(float4*)&Bv[4]  = bp[1];
    *(float4*)&Bv[8]  = bp[2];
    *(float4*)&Bv[12] = bp[3];
    float du = dtv * uv;
    sdt += dtv;
    #pragma unroll
    for (int n = 0; n < 16; ++n)
      h[n] = __expf(dtv * Av[n]) * h[n] + du * Bv[n];
  }
  alignas(16) __hip_bfloat16 fx[16];
  #pragma unroll
  for (int n = 0; n < 16; ++n) fx[n] = __float2bfloat16(h[n]);
  __hip_bfloat16* fo = F + (((size_t)c * BB + b) * DD + d) * NN;
  *(short8*)&fo[0] = *(short8*)&fx[0];
  *(short8*)&fo[8] = *(short8*)&fx[8];
  SD[((size_t)c * BB + b) * DD + d] = sdt;
}

__global__ __launch_bounds__(256) void k_scan_b(
    const __hip_bfloat16* __restrict__ F, const float* __restrict__ SD,
    const float* __restrict__ A_log, __hip_bfloat16* __restrict__ Hinit) {
  __shared__ float Ls[64 * 17];
  __shared__ float Ho[64 * 17];
  __shared__ float Ss[64];
  int bd = blockIdx.x;             // b*DD + d
  int b = bd / DD, d = bd % DD;
  int tid = threadIdx.x;
  if (tid < 128) {
    int c = tid >> 1, q = tid & 1;
    alignas(16) __hip_bfloat16 fx[8];
    *(short8*)fx = *(const short8*)(F + (((size_t)c * BB + b) * DD + d) * NN + q * 8);
    #pragma unroll
    for (int i = 0; i < 8; ++i)
      Ls[c * 17 + q * 8 + i] = __bfloat162float(fx[i]);
  }
  if (tid < 64) Ss[tid] = SD[((size_t)tid * BB + b) * DD + d];
  __syncthreads();
  int lane = tid & 63, w = tid >> 6;
  #pragma unroll
  for (int r = 0; r < 4; ++r) {
    int n = w * 4 + r;
    float Av = -__expf(A_log[(size_t)d * NN + n]);
    float Fv = Ls[lane * 17 + n];
    float Dv = __expf(Ss[lane] * Av);
    #pragma unroll
    for (int s = 1; s < 64; s <<= 1) {
      float Fp = __shfl_up(Fv, s);
      float Dp = __shfl_up(Dv, s);
      float nF = Fv + Dv * Fp;
      float nD = Dv * Dp;
      Fv = (lane >= s) ? nF : Fv;
      Dv = (lane >= s) ? nD : Dv;
    }
    float Hi = __shfl_up(Fv, 1);
    if (lane == 0) Hi = 0.f;
    Ho[lane * 17 + n] = Hi;
  }
  __syncthreads();
  if (tid < 128) {
    int c = tid >> 1, q = tid & 1;
    alignas(16) __hip_bfloat16 hx[8];
    #pragma unroll
    for (int i = 0; i < 8; ++i)
      hx[i] = __float2bfloat16(Ho[c * 17 + q * 8 + i]);
    *(short8*)(Hinit + (((size_t)c * BB + b) * DD + d) * NN + q * 8) = *(short8*)hx;
  }
}

__global__ __launch_bounds__(256) void k_scan_c(
    const __hip_bfloat16* __restrict__ dt, const __hip_bfloat16* __restrict__ ub,
    const float* __restrict__ Bm, const float* __restrict__ Cm,
    const float* __restrict__ A_log, const float* __restrict__ Dsk,
    const __hip_bfloat16* __restrict__ Hinit, float* __restrict__ hres,
    __hip_bfloat16* __restrict__ hb, int writeHb) {
  int c = blockIdx.x;
  int bd = blockIdx.y;
  int b = bd / 3;
  int d = (bd % 3) * 256 + threadIdx.x;
  float Av[16];
  {
    const float4* al = (const float4*)(A_log + (size_t)d * NN);
    #pragma unroll
    for (int q = 0; q < 4; ++q) {
      float4 v = al[q];
      Av[q * 4 + 0] = -__expf(v.x);
      Av[q * 4 + 1] = -__expf(v.y);
      Av[q * 4 + 2] = -__expf(v.z);
      Av[q * 4 + 3] = -__expf(v.w);
    }
  }
  float h[16];
  {
    alignas(16) __hip_bfloat16 hx[16];
    const __hip_bfloat16* hi = Hinit + (((size_t)c * BB + b) * DD + d) * NN;
    *(short8*)&hx[0] = *(const short8*)&hi[0];
    *(short8*)&hx[8] = *(const short8*)&hi[8];
    #pragma unroll
    for (int n = 0; n < 16; ++n) h[n] = __bfloat162float(hx[n]);
  }
  float dskip = Dsk[d];
  size_t base = ((size_t)b * LL + (size_t)c * CLEN) * DD + d;
  int row0 = c * CLEN + b * LL;
  #pragma unroll 4
  for (int t = 0; t < CLEN; ++t) {
    float dtv = __bfloat162float(dt[base + (size_t)t * DD]);
    float uv  = __bfloat162float(ub[base + (size_t)t * DD]);
    float Bv[16], Cv[16];
    const float4* bp = (const float4*)(Bm + (size_t)(row0 + t) * NN);
    const float4* cp = (const float4*)(Cm + (size_t)(row0 + t) * NN);
    *(float4*)&Bv[0]  = bp[0];
    *(float4*)&Bv[4]  = bp[1];
    *(float4*)&Bv[8]  = bp[2];
    *(float4*)&Bv[12] = bp[3];
    *(float4*)&Cv[0]  = cp[0];
    *(float4*)&Cv[4]  = cp[1];
    *(float4*)&Cv[8]  = cp[2];
    *(float4*)&Cv[12] = cp[3];
    float du = dtv * uv;
    float y = 0.f;
    #pragma unroll
    for (int n = 0; n < 16; ++n) {
      h[n] = __expf(dtv * Av[n]) * h[n] + du * Bv[n];
      y += h[n] * Cv[n];
    }
    float nh = hres[base + (size_t)t * DD] + y + dskip * uv;
    hres[base + (size_t)t * DD] = nh;
    if (writeHb) hb[base + (size_t)t * DD] = __float2bfloat16(nh);
  }
}

// ---------------- launch ----------------
extern "C" void kernel_launch(void* const* d_in, const int* in_sizes, int n_in,
                              void* d_out, int out_size, void* d_ws, size_t ws_size,
                              hipStream_t stream) {
  const int*   x     = (const int*)d_in[0];
  const float* emb   = (const float*)d_in[1];
  const float* convw = (const float*)d_in[2];
  const float* A_log = (const float*)d_in[3];
  const float* W_B   = (const float*)d_in[4];
  const float* W_C   = (const float*)d_in[5];
  const float* W_dt  = (const float*)d_in[6];
  const float* dt_b  = (const float*)d_in[7];
  const float* D_sk  = (const float*)d_in[8];
  const float* W1    = (const float*)d_in[9];
  const float* b1    = (const float*)d_in[10];
  const float* W2    = (const float*)d_in[11];
  const float* b2    = (const float*)d_in[12];
  const float* ng    = (const float*)d_in[13];
  const float* nb    = (const float*)d_in[14];
  const float* Wout  = (const float*)d_in[15];
  const float* bout  = (const float*)d_in[16];
  float* out = (float*)d_out;

  // converted dt/FFN weights live in d_out (dead until logits writes it)
  __hip_bfloat16* WTdt = (__hip_bfloat16*)d_out;            // 12*832*768
  __hip_bfloat16* WT1  = WTdt + (size_t)12 * 832 * DD;      // 4*3072*768
  __hip_bfloat16* WT2  = WT1  + (size_t)NLL * FF * DD;      // 4*768*3072
  // ends at ~53 MB < 262 MB out buffer

  char* p = (char*)d_ws;
  auto alloc = [&](size_t bytes) { char* r = p; p += (bytes + 255) & ~(size_t)255; return r; };
  float* h    = (float*)alloc((size_t)BL * DD * 4);
  float* Bm   = (float*)alloc((size_t)BL * NN * 4);
  float* Cm   = (float*)alloc((size_t)BL * NN * 4);
  float* SD   = (float*)alloc((size_t)CHK * BB * DD * 4);
  __hip_bfloat16* dtbb  = (__hip_bfloat16*)alloc((size_t)BL * DD * 2);
  __hip_bfloat16* F     = (__hip_bfloat16*)alloc((size_t)CHK * BB * DD * NN * 2);
  __hip_bfloat16* Hini  = (__hip_bfloat16*)alloc((size_t)CHK * BB * DD * NN * 2);
  __hip_bfloat16* ub    = (__hip_bfloat16*)alloc((size_t)BL * DD * 2);
  __hip_bfloat16* hb    = (__hip_bfloat16*)alloc((size_t)BL * DD * 2);
  __hip_bfloat16* fb    = (__hip_bfloat16*)alloc((size_t)BL * FF * 2);
  __hip_bfloat16* lnb   = (__hip_bfloat16*)alloc((size_t)BL * DD * 2);
  __hip_bfloat16* WTlog = (__hip_bfloat16*)alloc((size_t)VV * DD * 2);

  k_wconv_all<<<SEND, 256, 0, stream>>>(
      W_dt, W_B, W_C, W1, W2, Wout, WTdt, WT1, WT2, WTlog);
  k_embed<<<1536, 256, 0, stream>>>(x, emb, h);

  for (int l = 0; l < NLL; ++l) {
    for (int s = 0; s < NSS; ++s) {
      int ls = l * NSS + s;
      k_conv<<<1536, 256, 0, stream>>>(h, convw + (size_t)ls * DD * 3, ub);
      k_gemm_dtbc64<<<416, 256, 0, stream>>>(
          ub, WTdt + (size_t)ls * 832 * DD, dt_b + (size_t)ls * DD, dtbb, Bm, Cm);
      k_scan_a<<<dim3(CHK, 6), 256, 0, stream>>>(
          dtbb, ub, Bm, A_log + (size_t)ls * DD * NN, F, SD);
      k_scan_b<<<BB * DD, 256, 0, stream>>>(
          F, SD, A_log + (size_t)ls * DD * NN, Hini);
      k_scan_c<<<dim3(CHK, 6), 256, 0, stream>>>(
          dtbb, ub, Bm, Cm, A_log + (size_t)ls * DD * NN, D_sk + (size_t)ls * DD,
          Hini, h, hb, (s == NSS - 1) ? 1 : 0);
    }
    k_gemm_ffn1<<<384, 256, 0, stream>>>(
        hb, WT1 + (size_t)l * FF * DD, b1 + (size_t)l * FF, fb);
    k_gemm_ffn2s<<<768, 256, 0, stream>>>(
        fb, WT2 + (size_t)l * DD * FF, b2 + (size_t)l * DD, h);
  }

  k_layernorm<<<BL, 256, 0, stream>>>(h, ng, nb, lnb);
  k_gemm_logits2<<<dim3(VV / 128, BL / 256), 512, 0, stream>>>(
      lnb, WTlog, bout, out, BL, VV, DD);
}